// Round 3
// baseline (533.924 us; speedup 1.0000x reference)
//
#include <hip/hip_runtime.h>

// Problem constants (from reference):
//   bpe_features [B, LAYERS, L, D] fp32
//   layer_w      [LAYERS]          fp32
//   word_ids     [B, L]            int32 (word j covers tokens 2j, 2j+1)
//   out          [B, MAX_WORDS, D] fp32
#define BB 16
#define LAYERS 13
#define LL 512
#define DD 1024
#define WW 256   // MAX_WORDS

typedef float f32x4 __attribute__((ext_vector_type(4)));

// One block per (b, word). 256 threads, each owns one float4 slice of D.
//
// Max-MLP structure: all 26 independent global_load_dwordx4 are issued as one
// burst into a register array (no consumer between them), then a single
// implicit vmcnt wait precedes the FMA reduction. Membership scales (0/1)
// and 1/count factor out of the reduction entirely:
//   out = s0 * sum_l w_l * x[l, 2j] + s1 * sum_l w_l * x[l, 2j+1]
__global__ __launch_bounds__(256) void MorphologicalTagger_13657996001460_kernel(
    const float* __restrict__ bpe,       // [BB, LAYERS, LL, DD]
    const float* __restrict__ layer_w,   // [LAYERS]
    const int*   __restrict__ word_ids,  // [BB, LL]
    float*       __restrict__ out)       // [BB, WW, DD]
{
    const int blk = blockIdx.x;
    const int b   = blk >> 8;    // / WW
    const int j   = blk & 255;   // % WW
    const int tid = threadIdx.x; // 0..255, float4 index into D

    const int D4 = DD / 4;
    const f32x4* p =
        (const f32x4*)bpe + ((size_t)(b * LAYERS) * LL + (size_t)(2 * j)) * D4 + tid;
    const size_t lstride = (size_t)LL * D4;  // float4 stride between layers

    // ---- issue ALL 26 loads before any consumption (single vmcnt wait) ----
    f32x4 x0[LAYERS], x1[LAYERS];
#pragma unroll
    for (int l = 0; l < LAYERS; ++l) {
        x0[l] = __builtin_nontemporal_load(p + (size_t)l * lstride);
        x1[l] = __builtin_nontemporal_load(p + (size_t)l * lstride + D4);
    }

    // --- softmax weights (unnormalized exp; 1/sum folded into final scale) ---
    float w[LAYERS];
    float m = -3.402823e38f;
#pragma unroll
    for (int l = 0; l < LAYERS; ++l) {
        w[l] = layer_w[l];
        m = fmaxf(m, w[l]);
    }
    float s = 0.f;
#pragma unroll
    for (int l = 0; l < LAYERS; ++l) {
        w[l] = __expf(w[l] - m);
        s += w[l];
    }
    const float invs = 1.f / s;

    // --- segment membership for word j (tokens 2j, 2j+1), folded to scales ---
    const bool in0 = (word_ids[b * LL + 2 * j]     == j);
    const bool in1 = (word_ids[b * LL + 2 * j + 1] == j);
    const float cnt  = (in0 ? 1.f : 0.f) + (in1 ? 1.f : 0.f);
    const float rcnt = invs / fmaxf(cnt, 1.f);
    const float s0 = in0 ? rcnt : 0.f;
    const float s1 = in1 ? rcnt : 0.f;

    // ---- branch-free weighted reduction ----
    f32x4 a0 = (f32x4)0.f;
    f32x4 a1 = (f32x4)0.f;
#pragma unroll
    for (int l = 0; l < LAYERS; ++l) {
        a0 += w[l] * x0[l];
        a1 += w[l] * x1[l];
    }

    f32x4 r = s0 * a0 + s1 * a1;
    f32x4* op = (f32x4*)out + ((size_t)b * WW + j) * D4 + tid;
    __builtin_nontemporal_store(r, op);
}

extern "C" void kernel_launch(void* const* d_in, const int* in_sizes, int n_in,
                              void* d_out, int out_size, void* d_ws, size_t ws_size,
                              hipStream_t stream) {
    const float* bpe      = (const float*)d_in[0];  // [16,13,512,1024]
    const float* layer_w  = (const float*)d_in[1];  // [13]
    const int*   word_ids = (const int*)d_in[2];    // [16,512]
    float* out = (float*)d_out;                     // [16,256,1024]

    dim3 grid(BB * WW);   // 4096 blocks
    dim3 block(256);
    MorphologicalTagger_13657996001460_kernel<<<grid, block, 0, stream>>>(
        bpe, layer_w, word_ids, out);
}